// Round 1
// baseline (13717.844 us; speedup 1.0000x reference)
//
#include <hip/hip_runtime.h>

// Problem constants (T,B,I,H) = (1024, 64, 512, 512)
#define T_STEPS 1024
#define BATCH   64
#define IN_F    512
#define HID     512
#define G3      1536                 // 3*H
#define M_ROWS  (T_STEPS * BATCH)    // 65536

typedef _Float16 v8h  __attribute__((ext_vector_type(8)));
typedef _Float16 h2_t __attribute__((ext_vector_type(2)));
typedef float    v4f  __attribute__((ext_vector_type(4)));

__device__ __forceinline__ h2_t u2h(unsigned int u) { return __builtin_bit_cast(h2_t, u); }

// Packed f16 dot2 (v_dot2_f32_f16) with fp32 accumulate; fallback = unpack + fp32 FMA.
#if __has_builtin(__builtin_amdgcn_fdot2)
#define DOT2(acc, hu, wu) acc = __builtin_amdgcn_fdot2(u2h(hu), u2h(wu), acc, false)
#else
#define DOT2(acc, hu, wu) do { h2_t _h = u2h(hu), _w = u2h(wu); \
  acc += (float)_h[0] * (float)_w[0] + (float)_h[1] * (float)_w[1]; } while (0)
#endif

// ---------------------------------------------------------------------------
// Pack w_hh [1536][512] fp32 -> wp[k8][g][8] f16  (k-major groups of 8 for
// dot2 pairs + dwordx4 coalesced loads in the scan: adjacent g = adjacent 16B)
// ---------------------------------------------------------------------------
__global__ void prep_w(const float* __restrict__ whh, _Float16* __restrict__ wp) {
  const int g  = blockIdx.x * 256 + threadIdx.x;  // 0..1535 (gate row)
  const int k8 = blockIdx.y;                      // 0..63   (k/8)
  const float* s = whh + (size_t)g * HID + k8 * 8;
  float4 a = *(const float4*)s;
  float4 b = *(const float4*)(s + 4);
  v8h o = {(_Float16)a.x, (_Float16)a.y, (_Float16)a.z, (_Float16)a.w,
           (_Float16)b.x, (_Float16)b.y, (_Float16)b.z, (_Float16)b.w};
  *(v8h*)(wp + ((size_t)k8 * G3 + g) * 8) = o;
}

// ---------------------------------------------------------------------------
// gx = x[M=65536,K=512] * w_ih[N=1536,K=512]^T + b_ih   -> f16 [M][1536]
// 64x128 tile, BK=32, mfma_f32_16x16x32_f16, fp32->f16 convert during staging.
// A/B fragment: lane l holds row (l&15), k = (l>>4)*8 .. +8  (m120-verified).
// C/D: col = lane&15, row = (lane>>4)*4 + reg  (m89-verified, dtype-indep).
// ---------------------------------------------------------------------------
#define BM 64
#define BN 128
#define BK 32
#define LDP 40   // padded LDS row (halves): 80B stride breaks b128 bank conflicts

__global__ __launch_bounds__(256) void gemm_gx(
    const float* __restrict__ X, const float* __restrict__ W,
    const float* __restrict__ bias, _Float16* __restrict__ C) {
  __shared__ _Float16 As[BM][LDP];
  __shared__ _Float16 Bs[BN][LDP];
  const int tid  = threadIdx.x;
  const int lane = tid & 63;
  const int wave = tid >> 6;           // 4 waves: wave w -> rows w*16..+16
  const int m0 = blockIdx.y * BM;
  const int n0 = blockIdx.x * BN;

  v4f acc[8];
#pragma unroll
  for (int i = 0; i < 8; ++i) acc[i] = (v4f){0.f, 0.f, 0.f, 0.f};

  const int srow  = tid >> 2;          // staging: 4 threads per 32-wide row
  const int kpart = (tid & 3) * 8;
  const int fr = lane & 15;
  const int ko = (lane >> 4) * 8;

  for (int kc = 0; kc < IN_F; kc += BK) {
    {  // stage A tile 64x32 (fp32 load -> f16 LDS)
      const float* s = X + (size_t)(m0 + srow) * IN_F + kc + kpart;
      float4 a = *(const float4*)s;
      float4 b = *(const float4*)(s + 4);
      v8h o = {(_Float16)a.x, (_Float16)a.y, (_Float16)a.z, (_Float16)a.w,
               (_Float16)b.x, (_Float16)b.y, (_Float16)b.z, (_Float16)b.w};
      *(v8h*)&As[srow][kpart] = o;
    }
#pragma unroll
    for (int r = 0; r < 2; ++r) {  // stage B tile 128x32
      const float* s = W + (size_t)(n0 + r * 64 + srow) * IN_F + kc + kpart;
      float4 a = *(const float4*)s;
      float4 b = *(const float4*)(s + 4);
      v8h o = {(_Float16)a.x, (_Float16)a.y, (_Float16)a.z, (_Float16)a.w,
               (_Float16)b.x, (_Float16)b.y, (_Float16)b.z, (_Float16)b.w};
      *(v8h*)&Bs[r * 64 + srow][kpart] = o;
    }
    __syncthreads();
    v8h af = *(const v8h*)&As[wave * 16 + fr][ko];
#pragma unroll
    for (int nt = 0; nt < 8; ++nt) {
      v8h bf = *(const v8h*)&Bs[nt * 16 + fr][ko];
      acc[nt] = __builtin_amdgcn_mfma_f32_16x16x32_f16(af, bf, acc[nt], 0, 0, 0);
    }
    __syncthreads();
  }

  const int rq = lane >> 4;
#pragma unroll
  for (int nt = 0; nt < 8; ++nt) {
    const int gcol = n0 + nt * 16 + fr;
    const float bv = bias[gcol];
#pragma unroll
    for (int r = 0; r < 4; ++r) {
      const int grow = m0 + wave * 16 + rq * 4 + r;
      C[(size_t)grow * G3 + gcol] = (_Float16)(acc[nt][r] + bv);
    }
  }
}

// ---------------------------------------------------------------------------
// Sequential GRU scan. One workgroup per sequence (batch-parallel, no grid
// sync). 512 threads: thread j owns gate rows {j, j+512, j+1024} => three
// 512-long dot products per step via dot2; h lives in LDS as f16 (broadcast
// b128 reads), own-column h kept fp32 in a register for the z-blend.
// ---------------------------------------------------------------------------
__global__ __launch_bounds__(512) void gru_scan(
    const _Float16* __restrict__ gx, const _Float16* __restrict__ wp,
    const int* __restrict__ lens, const float* __restrict__ bhh,
    float* __restrict__ out) {
  const int b = blockIdx.x;
  const int j = threadIdx.x;
  __shared__ __align__(16) _Float16 hs[HID];
  hs[j] = (_Float16)0.f;
  float hreg = 0.f;
  const float bhr = bhh[j];
  const float bhz = bhh[j + HID];
  const float bhn = bhh[j + 2 * HID];
  const int len = lens[b];
  const uint4* wr_p = (const uint4*)wp + j;          // wp[k8][g][8]: 16B cells
  const uint4* wz_p = wr_p + HID;
  const uint4* wn_p = wr_p + 2 * HID;
  const uint4* hp = (const uint4*)hs;
  __syncthreads();

  for (int t = 0; t < len; ++t) {
    float accr = bhr, accz = bhz, accn = bhn;
#pragma unroll 4
    for (int k8 = 0; k8 < 64; ++k8) {
      const uint4 hv = hp[k8];                       // broadcast ds_read_b128
      const uint4 wr = wr_p[(size_t)k8 * G3];
      const uint4 wz = wz_p[(size_t)k8 * G3];
      const uint4 wn = wn_p[(size_t)k8 * G3];
      DOT2(accr, hv.x, wr.x); DOT2(accr, hv.y, wr.y);
      DOT2(accr, hv.z, wr.z); DOT2(accr, hv.w, wr.w);
      DOT2(accz, hv.x, wz.x); DOT2(accz, hv.y, wz.y);
      DOT2(accz, hv.z, wz.z); DOT2(accz, hv.w, wz.w);
      DOT2(accn, hv.x, wn.x); DOT2(accn, hv.y, wn.y);
      DOT2(accn, hv.z, wn.z); DOT2(accn, hv.w, wn.w);
    }
    const _Float16* gxr = gx + ((size_t)t * BATCH + b) * G3;
    const float xr = (float)gxr[j];
    const float xz = (float)gxr[j + HID];
    const float xn = (float)gxr[j + 2 * HID];
    __syncthreads();   // all hs reads of step t done before anyone rewrites hs
    const float r = 1.f / (1.f + __expf(-(xr + accr)));
    const float z = 1.f / (1.f + __expf(-(xz + accz)));
    const float pn = xn + r * accn;                      // b_hh_n inside r*( )
    const float n = 1.f - 2.f / (__expf(2.f * pn) + 1.f);  // tanh
    const float hnew = (1.f - z) * n + z * hreg;
    hreg = hnew;
    out[(size_t)t * (BATCH * HID) + b * HID + j] = hnew;
    hs[j] = (_Float16)hnew;
    __syncthreads();   // hs update visible before next step's matvec
  }
  // zero-pad past sequence end (d_out is poisoned 0xAA each launch)
  for (int t = len; t < T_STEPS; ++t)
    out[(size_t)t * (BATCH * HID) + b * HID + j] = 0.f;
  // h_last at offset T*B*H (hold semantics: h unchanged past len)
  out[(size_t)T_STEPS * BATCH * HID + (size_t)b * HID + j] = hreg;
}

// ---------------------------------------------------------------------------
extern "C" void kernel_launch(void* const* d_in, const int* in_sizes, int n_in,
                              void* d_out, int out_size, void* d_ws, size_t ws_size,
                              hipStream_t stream) {
  const float* x    = (const float*)d_in[0];
  const int*   lens = (const int*)d_in[1];
  const float* w_ih = (const float*)d_in[2];
  const float* w_hh = (const float*)d_in[3];
  const float* b_ih = (const float*)d_in[4];
  const float* b_hh = (const float*)d_in[5];
  float* out = (float*)d_out;

  // Workspace: gx f16 [65536][1536] = 192 MiB, packed w_hh f16 = 1.5 MiB
  _Float16* gxbuf = (_Float16*)d_ws;
  _Float16* wpack = gxbuf + (size_t)M_ROWS * G3;

  prep_w<<<dim3(G3 / 256, IN_F / 8), dim3(256), 0, stream>>>(w_hh, wpack);
  gemm_gx<<<dim3(G3 / BN, M_ROWS / BM), dim3(256), 0, stream>>>(x, w_ih, b_ih, gxbuf);
  gru_scan<<<dim3(BATCH), dim3(512), 0, stream>>>(gxbuf, wpack, lens, b_hh, out);
}